// Round 3
// baseline (773.304 us; speedup 1.0000x reference)
//
#include <hip/hip_runtime.h>

#define BS 2
#define NM 10
#define NA 8400
#define NC 80
#define NBIN 36
#define KTOP 13
#define NPAIR_MAX (BS*NM*NA)

// ---------------- zero kernels ----------------
__global__ void k_zero4(float4* __restrict__ p, int n4){
  int i = blockIdx.x*256 + threadIdx.x;
  if (i < n4) p[i] = make_float4(0.f,0.f,0.f,0.f);
}
__global__ void k_zero1(float* __restrict__ p, int n){
  int i = blockIdx.x*256 + threadIdx.x;
  if (i < n) p[i] = 0.f;
}

// ---------------- pair list: anchors strictly inside valid gt boxes ----------------
__global__ void k_masklist(const float* __restrict__ anc, const float* __restrict__ gtb,
                           const float* __restrict__ mgt, int* __restrict__ counter,
                           int* __restrict__ pairs){
  int t = blockIdx.x*256 + threadIdx.x;
  if (t >= BS*NM*NA) return;
  int a = t % NA; int bm = t / NA;
  if (mgt[bm] <= 0.f) return;
  float ax = anc[2*a], ay = anc[2*a+1];
  float lx = gtb[bm*4+0], ly = gtb[bm*4+1];
  float rx = gtb[bm*4+2], ry = gtb[bm*4+3];
  float mind = fminf(fminf(ax-lx, ay-ly), fminf(rx-ax, ry-ay));
  if (mind > 1e-9f){
    int i = atomicAdd(counter, 1);
    pairs[i] = t;
  }
}

// ---------------- hot kernel: per-pair dist_max(36) + IoU + align ----------------
// Angular-bucket pruning: bucket 360 contour points by nearest bin, then each
// bin scans only buckets within the provably-sufficient window. Selection uses
// lexicographic (diff, idx) keys -> identical set to lax.top_k stable ties.
__global__ __launch_bounds__(64)
void k_dist(const float* __restrict__ anc, const float* __restrict__ coor,
            const float* __restrict__ pdb, const float* __restrict__ pds,
            const int* __restrict__ gl,
            const int* __restrict__ counter, const int* __restrict__ pairs,
            float* __restrict__ w_align, float* __restrict__ w_ovl,
            float* __restrict__ o_gtdist){
  __shared__ float2 s_da[360];  // (dist, ang)
  __shared__ int    s_idx[360]; // bucket-compacted point indices
  __shared__ int    s_cnt[NBIN];
  __shared__ int    s_off[NBIN];
  __shared__ int    s_pos[NBIN];
  int lane = threadIdx.x;
  int cnt = counter[0];
  for (int p = blockIdx.x; p < cnt; p += gridDim.x){
    int t = pairs[p];
    int a = t % NA; int bm = t / NA; int b = bm / NM;
    float ax = anc[2*a], ay = anc[2*a+1];
    const float* cc = coor + bm*720;
    if (lane < NBIN){ s_cnt[lane] = 0; s_pos[lane] = 0; }
    __syncthreads();
    // pass 1: dist/ang + bucket counts
    int myb[6]; int nmine = 0;
    for (int i = lane; i < 360; i += 64){
      float dx = cc[2*i]   - ax;
      float dy = cc[2*i+1] - ay;
      float dist = sqrtf(dx*dx + dy*dy);
      float an = atan2f(dy, dx) * 57.29577951308232f;
      if (an < 0.f) an += 360.f;
      s_da[i] = make_float2(dist, an);
      int bkt = (int)(an*0.1f + 0.5f); if (bkt >= NBIN) bkt -= NBIN;
      myb[nmine++] = bkt;
      atomicAdd(&s_cnt[bkt], 1);
    }
    __syncthreads();
    if (lane == 0){
      int acc = 0;
      for (int j = 0; j < NBIN; j++){ s_off[j] = acc; acc += s_cnt[j]; }
    }
    __syncthreads();
    // pass 2: scatter indices into bucket lists
    {
      int n2 = 0;
      for (int i = lane; i < 360; i += 64){
        int bkt = myb[n2++];
        int slot = atomicAdd(&s_pos[bkt], 1);
        s_idx[s_off[bkt] + slot] = i;
      }
    }
    __syncthreads();
    // scan: per-bin exact top-4 over windowed candidates
    float sum_min = 0.f, sum_max = 0.f;
    if (lane < NBIN){
      float th = (float)(lane*10);
      int c = s_cnt[lane]; int d = 0;
      while (c < 4 && d < 18){
        d++;
        c += s_cnt[(lane + d) % NBIN];
        if (d < 18) c += s_cnt[(lane + NBIN - d) % NBIN];
      }
      int dscan = d + 1; if (dscan > 18) dscan = 18;
      float v0=1e30f, v1=1e30f, v2=1e30f, v3=1e30f;
      int   i0=0x7fffffff, i1=0x7fffffff, i2=0x7fffffff, i3=0x7fffffff;
      for (int dd = 0; dd <= dscan; dd++){
        int b1 = (lane + dd) % NBIN;
        int b2 = (lane + NBIN - dd) % NBIN;
#pragma unroll
        for (int side = 0; side < 2; side++){
          int bkt = side ? b2 : b1;
          if (side && b2 == b1) continue;
          int o = s_off[bkt], n = s_cnt[bkt];
          for (int k = 0; k < n; k++){
            int idx = s_idx[o + k];
            float diff = fabsf(s_da[idx].y - th);
            diff = (diff > 180.f) ? (360.f - diff) : diff;
            if (diff < v3 || (diff == v3 && idx < i3)){
              v3 = diff; i3 = idx;
              if (v3 < v2 || (v3 == v2 && i3 < i2)){
                float tv=v2; v2=v3; v3=tv; int ti=i2; i2=i3; i3=ti; }
              if (v2 < v1 || (v2 == v1 && i2 < i1)){
                float tv=v1; v1=v2; v2=tv; int ti=i1; i1=i2; i2=ti; }
              if (v1 < v0 || (v1 == v0 && i1 < i0)){
                float tv=v0; v0=v1; v1=tv; int ti=i0; i0=i1; i1=ti; }
            }
          }
        }
      }
      float dm;
      if (v0 > 3.0f) dm = 1e-6f;
      else dm = fmaxf(fmaxf(s_da[i0].x, s_da[i1].x), fmaxf(s_da[i2].x, s_da[i3].x));
      float dmax = fmaxf(dm, 1e-6f);
      o_gtdist[(size_t)t*NBIN + lane] = dmax;
      float pr = pdb[((size_t)b*NA + a)*NBIN + lane];
      sum_max = fmaxf(dmax, pr);
      sum_min = fmaxf(fminf(dmax, pr), 1e-6f);
    }
    for (int off = 32; off > 0; off >>= 1){
      sum_min += __shfl_down(sum_min, off);
      sum_max += __shfl_down(sum_max, off);
    }
    if (lane == 0){
      float ov = sum_min / sum_max;
      int cls = gl[bm];
      float sc = pds[((size_t)b*NA + a)*NC + cls];
      w_align[t] = sc * ov * ov * ov;
      w_ovl[t]   = ov;
    }
    __syncthreads();
  }
}

// ---------------- top-13 per (b,m): single pass + k-way merge ----------------
__global__ __launch_bounds__(256)
void k_topk(const float* __restrict__ w_align, float* __restrict__ w_mask){
  int bm = blockIdx.x;
  const float* al = w_align + (size_t)bm*NA;
  int tid = threadIdx.x;
  __shared__ float sv[256*KTOP];
  __shared__ int   si[256*KTOP];
  __shared__ float wv4[4];
  __shared__ int   wi4[4];

  float v[KTOP]; int ix[KTOP];
#pragma unroll
  for (int j = 0; j < KTOP; j++){ v[j] = -1.f; ix[j] = 0x7fffffff; }
  for (int a = tid; a < NA; a += 256){
    float x = al[a];
    if (x > v[KTOP-1]){
      v[KTOP-1] = x; ix[KTOP-1] = a;
#pragma unroll
      for (int j = KTOP-1; j > 0; j--){
        if (v[j] > v[j-1]){
          float tv = v[j-1]; v[j-1] = v[j]; v[j] = tv;
          int   ti = ix[j-1]; ix[j-1] = ix[j]; ix[j] = ti;
        }
      }
    }
  }
#pragma unroll
  for (int j = 0; j < KTOP; j++){ sv[tid*KTOP+j] = v[j]; si[tid*KTOP+j] = ix[j]; }

  int head = 0;
  int lane = tid & 63, wave = tid >> 6;
  for (int r = 0; r < KTOP; r++){
    float cv = sv[tid*KTOP + head];
    int   ci = si[tid*KTOP + head];
    float rv = cv; int ri = ci;
    for (int off = 32; off > 0; off >>= 1){
      float ov = __shfl_down(rv, off);
      int   oi = __shfl_down(ri, off);
      if (ov > rv || (ov == rv && oi < ri)){ rv = ov; ri = oi; }
    }
    if (lane == 0){ wv4[wave] = rv; wi4[wave] = ri; }
    __syncthreads();
    float Wv = wv4[0]; int Wi = wi4[0];
#pragma unroll
    for (int w = 1; w < 4; w++){
      float ov = wv4[w]; int oi = wi4[w];
      if (ov > Wv || (ov == Wv && oi < Wi)){ Wv = ov; Wi = oi; }
    }
    if (ci == Wi && head < KTOP-1) head++;
    if (tid == 0 && Wv > 0.f) w_mask[(size_t)bm*NA + Wi] = 1.f;
    __syncthreads();
  }
}

// ---------------- per-anchor finalize ----------------
__global__ void k_final(const float* __restrict__ w_ovl, float* __restrict__ w_mask,
                        const int* __restrict__ gl, const float* __restrict__ gtb,
                        float* __restrict__ o_labels, float* __restrict__ o_bboxes,
                        float* __restrict__ o_maskpos, float* __restrict__ o_gtidx,
                        float* __restrict__ o_fg){
  int t = blockIdx.x*256 + threadIdx.x;
  if (t >= BS*NA) return;
  int a = t % NA, b = t / NA;
  float mp[NM];
  int fg = 0;
#pragma unroll
  for (int m = 0; m < NM; m++){
    mp[m] = w_mask[((size_t)(b*NM+m))*NA + a];
    fg += (mp[m] > 0.f) ? 1 : 0;
  }
  if (fg > 1){
    float bv = -1.f; int bi = 0;
#pragma unroll
    for (int m = 0; m < NM; m++){
      float v = w_ovl[((size_t)(b*NM+m))*NA + a];
      if (v > bv){ bv = v; bi = m; }
    }
#pragma unroll
    for (int m = 0; m < NM; m++){
      mp[m] = (m == bi) ? 1.f : 0.f;
      w_mask[((size_t)(b*NM+m))*NA + a] = mp[m];
    }
    fg = 1;
  }
  int tgt = 0;
#pragma unroll
  for (int m = NM-1; m >= 0; m--) if (mp[m] > 0.f) tgt = m;
#pragma unroll
  for (int m = 0; m < NM; m++) o_maskpos[((size_t)(b*NM+m))*NA + a] = mp[m];
  o_gtidx[t] = (float)tgt;
  o_fg[t] = (fg > 0) ? 1.f : 0.f;
  int lbl = gl[b*NM + tgt]; if (lbl < 0) lbl = 0;
  o_labels[t] = (float)lbl;
  const float* bx = gtb + (b*NM + tgt)*4;
  ((float4*)o_bboxes)[t] = make_float4(bx[0], bx[1], bx[2], bx[3]);
}

// ---------------- per-(b,m) pos_align / pos_ov ----------------
__global__ void k_posmax(const float* __restrict__ w_align, const float* __restrict__ w_ovl,
                         const float* __restrict__ w_mask,
                         float* __restrict__ w_pa, float* __restrict__ w_po){
  int bm = blockIdx.x;
  __shared__ float sa[256], so[256];
  int tid = threadIdx.x;
  float ma = 0.f, mo = 0.f;
  for (int a = tid; a < NA; a += 256){
    float m = w_mask[(size_t)bm*NA + a];
    if (m > 0.f){
      ma = fmaxf(ma, w_align[(size_t)bm*NA + a]);
      mo = fmaxf(mo, w_ovl[(size_t)bm*NA + a]);
    }
  }
  sa[tid] = ma; so[tid] = mo;
  __syncthreads();
  for (int s = 128; s > 0; s >>= 1){
    if (tid < s){
      sa[tid] = fmaxf(sa[tid], sa[tid+s]);
      so[tid] = fmaxf(so[tid], so[tid+s]);
    }
    __syncthreads();
  }
  if (tid == 0){ w_pa[bm] = sa[0]; w_po[bm] = so[0]; }
}

// ---------------- per-anchor norm_align -> one-hot score ----------------
__global__ void k_scores(const float* __restrict__ w_align, const float* __restrict__ w_mask,
                         const float* __restrict__ w_pa, const float* __restrict__ w_po,
                         const float* __restrict__ o_labels, const float* __restrict__ o_fg,
                         float* __restrict__ o_scores){
  int t = blockIdx.x*256 + threadIdx.x;
  if (t >= BS*NA) return;
  int a = t % NA, b = t / NA;
  float norm = 0.f;
#pragma unroll
  for (int m = 0; m < NM; m++){
    int bm = b*NM + m;
    float am = w_align[(size_t)bm*NA + a] * w_mask[(size_t)bm*NA + a];
    norm = fmaxf(norm, am * w_po[bm] / (w_pa[bm] + 1e-9f));
  }
  if (o_fg[t] > 0.f){
    int lbl = (int)o_labels[t];
    o_scores[(size_t)t*NC + lbl] = norm;
  }
}

// ---------------- pair-list pass: gt_dist masking + centerness ----------------
__global__ __launch_bounds__(64)
void k_fix(const int* __restrict__ counter, const int* __restrict__ pairs,
           const float* __restrict__ w_mask, float* __restrict__ o_gtdist,
           float* __restrict__ o_cent){
  int lane = threadIdx.x;
  int cnt = counter[0];
  for (int p = blockIdx.x; p < cnt; p += gridDim.x){
    int t = pairs[p];
    float m = w_mask[t];
    float* row = o_gtdist + (size_t)t*NBIN;
    if (m > 0.f){
      float vmin = 1e30f, vmax = 0.f;
      if (lane < NBIN){
        float v = row[lane];
        vmin = v; vmax = v;
      }
      for (int off = 32; off > 0; off >>= 1){
        vmin = fminf(vmin, __shfl_down(vmin, off));
        vmax = fmaxf(vmax, __shfl_down(vmax, off));
      }
      if (lane == 0) o_cent[t] = sqrtf(vmin / vmax);
    } else {
      if (lane < NBIN) row[lane] = 0.f;
    }
  }
}

extern "C" void kernel_launch(void* const* d_in, const int* in_sizes, int n_in,
                              void* d_out, int out_size, void* d_ws, size_t ws_size,
                              hipStream_t stream){
  const float* pds  = (const float*)d_in[0]; // (2,8400,80)
  const float* pdb  = (const float*)d_in[1]; // (2,8400,36)
  const float* anc  = (const float*)d_in[2]; // (8400,2)
  const int*   gl   = (const int*)  d_in[3]; // (2,10,1)
  const float* gtb  = (const float*)d_in[4]; // (2,10,4)
  const float* mgt  = (const float*)d_in[5]; // (2,10,1)
  const float* coor = (const float*)d_in[6]; // (2,10,720)

  float* out = (float*)d_out;
  float* o_labels  = out;                                 // 16800
  float* o_bboxes  = o_labels + BS*NA;                    // 67200
  float* o_scores  = o_bboxes + BS*NA*4;                  // 1344000
  float* o_maskpos = o_scores + (size_t)BS*NA*NC;         // 168000
  float* o_gtidx   = o_maskpos + BS*NM*NA;                // 16800
  float* o_gtdist  = o_gtidx + BS*NA;                     // 6048000
  float* o_cent    = o_gtdist + (size_t)BS*NM*NA*NBIN;    // 168000
  float* o_fg      = o_cent + BS*NM*NA;                   // 16800

  float* wf      = (float*)d_ws;
  int*   counter = (int*)d_ws;           // wf[0]
  float* w_align = wf + 16;              // 168000
  float* w_ovl   = w_align + BS*NM*NA;   // 168000
  float* w_mask  = w_ovl + BS*NM*NA;     // 168000
  float* w_pa    = w_mask + BS*NM*NA;    // 20
  float* w_po    = w_pa + BS*NM;         // 20
  int*   w_pairs = (int*)(w_po + BS*NM); // up to 168000

  int n4 = out_size / 4;
  k_zero4<<<(n4+255)/256, 256, 0, stream>>>((float4*)out, n4);
  int nz = 16 + 3*BS*NM*NA;
  k_zero1<<<(nz+255)/256, 256, 0, stream>>>(wf, nz);
  k_masklist<<<(BS*NM*NA+255)/256, 256, 0, stream>>>(anc, gtb, mgt, counter, w_pairs);
  k_dist<<<6144, 64, 0, stream>>>(anc, coor, pdb, pds, gl, counter, w_pairs,
                                  w_align, w_ovl, o_gtdist);
  k_topk<<<BS*NM, 256, 0, stream>>>(w_align, w_mask);
  k_final<<<(BS*NA+255)/256, 256, 0, stream>>>(w_ovl, w_mask, gl, gtb,
                                               o_labels, o_bboxes, o_maskpos, o_gtidx, o_fg);
  k_posmax<<<BS*NM, 256, 0, stream>>>(w_align, w_ovl, w_mask, w_pa, w_po);
  k_scores<<<(BS*NA+255)/256, 256, 0, stream>>>(w_align, w_mask, w_pa, w_po,
                                                o_labels, o_fg, o_scores);
  k_fix<<<4096, 64, 0, stream>>>(counter, w_pairs, w_mask, o_gtdist, o_cent);
}

// Round 4
// 201.976 us; speedup vs baseline: 3.8287x; 3.8287x over previous
//
#include <hip/hip_runtime.h>

#define BS 2
#define NM 10
#define NA 8400
#define NC 80
#define NBIN 36
#define KTOP 13
#define NPAIR_MAX (BS*NM*NA)

// ---------------- merged zero kernel: d_out (float4) + ws header ----------------
__global__ void k_zero(float4* __restrict__ out4, int n4,
                       float* __restrict__ wf, int nz){
  int i = blockIdx.x*256 + threadIdx.x;
  if (i < n4) out4[i] = make_float4(0.f,0.f,0.f,0.f);
  if (i < nz) wf[i] = 0.f;
}

// ---------------- pair list: anchors strictly inside valid gt boxes ----------------
__global__ void k_masklist(const float* __restrict__ anc, const float* __restrict__ gtb,
                           const float* __restrict__ mgt, int* __restrict__ counter,
                           int* __restrict__ pairs){
  int t = blockIdx.x*256 + threadIdx.x;
  if (t >= BS*NM*NA) return;
  int a = t % NA; int bm = t / NA;
  if (mgt[bm] <= 0.f) return;
  float ax = anc[2*a], ay = anc[2*a+1];
  float lx = gtb[bm*4+0], ly = gtb[bm*4+1];
  float rx = gtb[bm*4+2], ry = gtb[bm*4+3];
  float mind = fminf(fminf(ax-lx, ay-ly), fminf(rx-ax, ry-ay));
  if (mind > 1e-9f){
    int i = atomicAdd(counter, 1);
    pairs[i] = t;
  }
}

// ---------------- hot kernel: per-pair dist_max(36) + IoU + align ----------------
// Uniform broadcast scan (round-1 structure): all lanes read the SAME LDS
// address each iteration (bank broadcast = free), fixed 360-trip loop, no
// divergence. One wave per pair; grid sized so ~every pair is resident.
__global__ __launch_bounds__(64)
void k_dist(const float* __restrict__ anc, const float* __restrict__ coor,
            const float* __restrict__ pdb, const float* __restrict__ pds,
            const int* __restrict__ gl,
            const int* __restrict__ counter, const int* __restrict__ pairs,
            float* __restrict__ w_align, float* __restrict__ w_ovl,
            float* __restrict__ o_gtdist){
  __shared__ float2 s_da[360]; // x = dist, y = angle(deg, [0,360))
  int lane = threadIdx.x;
  int cnt = counter[0];
  for (int p = blockIdx.x; p < cnt; p += gridDim.x){
    int t = pairs[p];
    int a = t % NA; int bm = t / NA; int b = bm / NM;
    float ax = anc[2*a], ay = anc[2*a+1];
    const float* cc = coor + bm*720;
    for (int i = lane; i < 360; i += 64){
      float dx = cc[2*i]   - ax;
      float dy = cc[2*i+1] - ay;
      float dist = sqrtf(dx*dx + dy*dy);
      float an = atan2f(dy, dx) * 57.29577951308232f;
      if (an < 0.f) an += 360.f;
      s_da[i] = make_float2(dist, an);
    }
    __syncthreads();
    float sum_min = 0.f, sum_max = 0.f;
    if (lane < NBIN){
      float th = (float)(lane*10);
      float v0=1e30f, v1=1e30f, v2=1e30f, v3=1e30f;
      float d0=0.f, d1=0.f, d2=0.f, d3=0.f;
      for (int i = 0; i < 360; i++){
        float2 da = s_da[i];
        float diff = fabsf(da.y - th);
        diff = fminf(diff, 360.f - diff);
        if (diff < v3){
          v3 = diff; d3 = da.x;
          if (v3 < v2){ float tv=v2; v2=v3; v3=tv; float td=d2; d2=d3; d3=td; }
          if (v2 < v1){ float tv=v1; v1=v2; v2=tv; float td=d1; d1=d2; d2=td; }
          if (v1 < v0){ float tv=v0; v0=v1; v1=tv; float td=d0; d0=d1; d1=td; }
        }
      }
      float dm;
      if (v0 > 3.0f) dm = 1e-6f;
      else dm = fmaxf(fmaxf(d0,d1), fmaxf(d2,d3));
      float dmax = fmaxf(dm, 1e-6f);
      o_gtdist[(size_t)t*NBIN + lane] = dmax;
      float pr = pdb[((size_t)b*NA + a)*NBIN + lane];
      sum_max = fmaxf(dmax, pr);
      sum_min = fmaxf(fminf(dmax, pr), 1e-6f);
    }
    // wave reduce (lanes >= 36 contribute 0)
    for (int off = 32; off > 0; off >>= 1){
      sum_min += __shfl_down(sum_min, off);
      sum_max += __shfl_down(sum_max, off);
    }
    if (lane == 0){
      float ov = sum_min / sum_max;
      int cls = gl[bm];
      float sc = pds[((size_t)b*NA + a)*NC + cls];
      w_align[t] = sc * ov * ov * ov;
      w_ovl[t]   = ov;
    }
    __syncthreads();
  }
}

// ---------------- top-13 per (b,m): single pass + k-way merge ----------------
__global__ __launch_bounds__(256)
void k_topk(const float* __restrict__ w_align, float* __restrict__ w_mask){
  int bm = blockIdx.x;
  const float* al = w_align + (size_t)bm*NA;
  int tid = threadIdx.x;
  __shared__ float sv[256*KTOP];
  __shared__ int   si[256*KTOP];
  __shared__ float wv4[4];
  __shared__ int   wi4[4];

  float v[KTOP]; int ix[KTOP];
#pragma unroll
  for (int j = 0; j < KTOP; j++){ v[j] = -1.f; ix[j] = 0x7fffffff; }
  for (int a = tid; a < NA; a += 256){
    float x = al[a];
    if (x > v[KTOP-1]){
      v[KTOP-1] = x; ix[KTOP-1] = a;
#pragma unroll
      for (int j = KTOP-1; j > 0; j--){
        if (v[j] > v[j-1]){
          float tv = v[j-1]; v[j-1] = v[j]; v[j] = tv;
          int   ti = ix[j-1]; ix[j-1] = ix[j]; ix[j] = ti;
        }
      }
    }
  }
#pragma unroll
  for (int j = 0; j < KTOP; j++){ sv[tid*KTOP+j] = v[j]; si[tid*KTOP+j] = ix[j]; }

  int head = 0;
  int lane = tid & 63, wave = tid >> 6;
  for (int r = 0; r < KTOP; r++){
    float cv = sv[tid*KTOP + head];
    int   ci = si[tid*KTOP + head];
    float rv = cv; int ri = ci;
    for (int off = 32; off > 0; off >>= 1){
      float ov = __shfl_down(rv, off);
      int   oi = __shfl_down(ri, off);
      if (ov > rv || (ov == rv && oi < ri)){ rv = ov; ri = oi; }
    }
    if (lane == 0){ wv4[wave] = rv; wi4[wave] = ri; }
    __syncthreads();
    float Wv = wv4[0]; int Wi = wi4[0];
#pragma unroll
    for (int w = 1; w < 4; w++){
      float ov = wv4[w]; int oi = wi4[w];
      if (ov > Wv || (ov == Wv && oi < Wi)){ Wv = ov; Wi = oi; }
    }
    if (ci == Wi && head < KTOP-1) head++;
    if (tid == 0 && Wv > 0.f) w_mask[(size_t)bm*NA + Wi] = 1.f;
    __syncthreads();
  }
}

// ---------------- per-anchor finalize ----------------
__global__ void k_final(const float* __restrict__ w_ovl, float* __restrict__ w_mask,
                        const int* __restrict__ gl, const float* __restrict__ gtb,
                        float* __restrict__ o_labels, float* __restrict__ o_bboxes,
                        float* __restrict__ o_maskpos, float* __restrict__ o_gtidx,
                        float* __restrict__ o_fg){
  int t = blockIdx.x*256 + threadIdx.x;
  if (t >= BS*NA) return;
  int a = t % NA, b = t / NA;
  float mp[NM];
  int fg = 0;
#pragma unroll
  for (int m = 0; m < NM; m++){
    mp[m] = w_mask[((size_t)(b*NM+m))*NA + a];
    fg += (mp[m] > 0.f) ? 1 : 0;
  }
  if (fg > 1){
    float bv = -1.f; int bi = 0;
#pragma unroll
    for (int m = 0; m < NM; m++){
      float v = w_ovl[((size_t)(b*NM+m))*NA + a];
      if (v > bv){ bv = v; bi = m; }
    }
#pragma unroll
    for (int m = 0; m < NM; m++){
      mp[m] = (m == bi) ? 1.f : 0.f;
      w_mask[((size_t)(b*NM+m))*NA + a] = mp[m];
    }
    fg = 1;
  }
  int tgt = 0;
#pragma unroll
  for (int m = NM-1; m >= 0; m--) if (mp[m] > 0.f) tgt = m;
#pragma unroll
  for (int m = 0; m < NM; m++) o_maskpos[((size_t)(b*NM+m))*NA + a] = mp[m];
  o_gtidx[t] = (float)tgt;
  o_fg[t] = (fg > 0) ? 1.f : 0.f;
  int lbl = gl[b*NM + tgt]; if (lbl < 0) lbl = 0;
  o_labels[t] = (float)lbl;
  const float* bx = gtb + (b*NM + tgt)*4;
  ((float4*)o_bboxes)[t] = make_float4(bx[0], bx[1], bx[2], bx[3]);
}

// ---------------- per-(b,m) pos_align / pos_ov ----------------
__global__ void k_posmax(const float* __restrict__ w_align, const float* __restrict__ w_ovl,
                         const float* __restrict__ w_mask,
                         float* __restrict__ w_pa, float* __restrict__ w_po){
  int bm = blockIdx.x;
  __shared__ float sa[256], so[256];
  int tid = threadIdx.x;
  float ma = 0.f, mo = 0.f;
  for (int a = tid; a < NA; a += 256){
    float m = w_mask[(size_t)bm*NA + a];
    if (m > 0.f){
      ma = fmaxf(ma, w_align[(size_t)bm*NA + a]);
      mo = fmaxf(mo, w_ovl[(size_t)bm*NA + a]);
    }
  }
  sa[tid] = ma; so[tid] = mo;
  __syncthreads();
  for (int s = 128; s > 0; s >>= 1){
    if (tid < s){
      sa[tid] = fmaxf(sa[tid], sa[tid+s]);
      so[tid] = fmaxf(so[tid], so[tid+s]);
    }
    __syncthreads();
  }
  if (tid == 0){ w_pa[bm] = sa[0]; w_po[bm] = so[0]; }
}

// ---------------- per-anchor norm_align -> one-hot score ----------------
__global__ void k_scores(const float* __restrict__ w_align, const float* __restrict__ w_mask,
                         const float* __restrict__ w_pa, const float* __restrict__ w_po,
                         const float* __restrict__ o_labels, const float* __restrict__ o_fg,
                         float* __restrict__ o_scores){
  int t = blockIdx.x*256 + threadIdx.x;
  if (t >= BS*NA) return;
  int a = t % NA, b = t / NA;
  float norm = 0.f;
#pragma unroll
  for (int m = 0; m < NM; m++){
    int bm = b*NM + m;
    float am = w_align[(size_t)bm*NA + a] * w_mask[(size_t)bm*NA + a];
    norm = fmaxf(norm, am * w_po[bm] / (w_pa[bm] + 1e-9f));
  }
  if (o_fg[t] > 0.f){
    int lbl = (int)o_labels[t];
    o_scores[(size_t)t*NC + lbl] = norm;
  }
}

// ---------------- pair-list pass: gt_dist masking + centerness ----------------
__global__ __launch_bounds__(64)
void k_fix(const int* __restrict__ counter, const int* __restrict__ pairs,
           const float* __restrict__ w_mask, float* __restrict__ o_gtdist,
           float* __restrict__ o_cent){
  int lane = threadIdx.x;
  int cnt = counter[0];
  for (int p = blockIdx.x; p < cnt; p += gridDim.x){
    int t = pairs[p];
    float m = w_mask[t];
    float* row = o_gtdist + (size_t)t*NBIN;
    if (m > 0.f){
      float vmin = 1e30f, vmax = 0.f;
      if (lane < NBIN){
        float v = row[lane];
        vmin = v; vmax = v;
      }
      for (int off = 32; off > 0; off >>= 1){
        vmin = fminf(vmin, __shfl_down(vmin, off));
        vmax = fmaxf(vmax, __shfl_down(vmax, off));
      }
      if (lane == 0) o_cent[t] = sqrtf(vmin / vmax);
    } else {
      if (lane < NBIN) row[lane] = 0.f;
    }
  }
}

extern "C" void kernel_launch(void* const* d_in, const int* in_sizes, int n_in,
                              void* d_out, int out_size, void* d_ws, size_t ws_size,
                              hipStream_t stream){
  const float* pds  = (const float*)d_in[0]; // (2,8400,80)
  const float* pdb  = (const float*)d_in[1]; // (2,8400,36)
  const float* anc  = (const float*)d_in[2]; // (8400,2)
  const int*   gl   = (const int*)  d_in[3]; // (2,10,1)
  const float* gtb  = (const float*)d_in[4]; // (2,10,4)
  const float* mgt  = (const float*)d_in[5]; // (2,10,1)
  const float* coor = (const float*)d_in[6]; // (2,10,720)

  float* out = (float*)d_out;
  float* o_labels  = out;                                 // 16800
  float* o_bboxes  = o_labels + BS*NA;                    // 67200
  float* o_scores  = o_bboxes + BS*NA*4;                  // 1344000
  float* o_maskpos = o_scores + (size_t)BS*NA*NC;         // 168000
  float* o_gtidx   = o_maskpos + BS*NM*NA;                // 16800
  float* o_gtdist  = o_gtidx + BS*NA;                     // 6048000
  float* o_cent    = o_gtdist + (size_t)BS*NM*NA*NBIN;    // 168000
  float* o_fg      = o_cent + BS*NM*NA;                   // 16800

  float* wf      = (float*)d_ws;
  int*   counter = (int*)d_ws;           // wf[0]
  float* w_align = wf + 16;              // 168000
  float* w_ovl   = w_align + BS*NM*NA;   // 168000
  float* w_mask  = w_ovl + BS*NM*NA;     // 168000
  float* w_pa    = w_mask + BS*NM*NA;    // 20
  float* w_po    = w_pa + BS*NM;         // 20
  int*   w_pairs = (int*)(w_po + BS*NM); // up to 168000

  int n4 = out_size / 4;
  int nz = 16 + 3*BS*NM*NA;
  int nmax = (n4 > nz) ? n4 : nz;
  k_zero<<<(nmax+255)/256, 256, 0, stream>>>((float4*)out, n4, wf, nz);
  k_masklist<<<(BS*NM*NA+255)/256, 256, 0, stream>>>(anc, gtb, mgt, counter, w_pairs);
  k_dist<<<6144, 64, 0, stream>>>(anc, coor, pdb, pds, gl, counter, w_pairs,
                                  w_align, w_ovl, o_gtdist);
  k_topk<<<BS*NM, 256, 0, stream>>>(w_align, w_mask);
  k_final<<<(BS*NA+255)/256, 256, 0, stream>>>(w_ovl, w_mask, gl, gtb,
                                               o_labels, o_bboxes, o_maskpos, o_gtidx, o_fg);
  k_posmax<<<BS*NM, 256, 0, stream>>>(w_align, w_ovl, w_mask, w_pa, w_po);
  k_scores<<<(BS*NA+255)/256, 256, 0, stream>>>(w_align, w_mask, w_pa, w_po,
                                                o_labels, o_fg, o_scores);
  k_fix<<<4096, 64, 0, stream>>>(counter, w_pairs, w_mask, o_gtdist, o_cent);
}

// Round 5
// 182.208 us; speedup vs baseline: 4.2441x; 1.1085x over previous
//
#include <hip/hip_runtime.h>

#define BS 2
#define NM 10
#define NA 8400
#define NC 80
#define NBIN 36
#define KTOP 13
#define NPAIR_MAX (BS*NM*NA)

// ---------------- merged zero kernel: d_out (float4) + ws header ----------------
__global__ void k_zero(float4* __restrict__ out4, int n4,
                       float* __restrict__ wf, int nz){
  int i = blockIdx.x*256 + threadIdx.x;
  if (i < n4) out4[i] = make_float4(0.f,0.f,0.f,0.f);
  if (i < nz) wf[i] = 0.f;
}

// ---------------- pair list: anchors strictly inside valid gt boxes ----------------
__global__ void k_masklist(const float* __restrict__ anc, const float* __restrict__ gtb,
                           const float* __restrict__ mgt, int* __restrict__ counter,
                           int* __restrict__ pairs){
  int t = blockIdx.x*256 + threadIdx.x;
  if (t >= BS*NM*NA) return;
  int a = t % NA; int bm = t / NA;
  if (mgt[bm] <= 0.f) return;
  float ax = anc[2*a], ay = anc[2*a+1];
  float lx = gtb[bm*4+0], ly = gtb[bm*4+1];
  float rx = gtb[bm*4+2], ry = gtb[bm*4+3];
  float mind = fminf(fminf(ax-lx, ay-ly), fminf(rx-ax, ry-ay));
  if (mind > 1e-9f){
    int i = atomicAdd(counter, 1);
    pairs[i] = t;
  }
}

// ---------------- hot kernel: per-pair dist_max(36) + IoU + align ----------------
// 4 waves per pair: each wave scans a 90-point quarter (uniform LDS broadcast,
// no divergence), keeping per-bin sorted top-4 (diff asc, scan order = stable).
// Wave 0 then does an exact stable 4-way merge (prefer lower wave on ties ==
// original 0..359 scan order), preserving lax.top_k tie semantics exactly.
__global__ __launch_bounds__(256)
void k_dist(const float* __restrict__ anc, const float* __restrict__ coor,
            const float* __restrict__ pdb, const float* __restrict__ pds,
            const int* __restrict__ gl,
            const int* __restrict__ counter, const int* __restrict__ pairs,
            float* __restrict__ w_align, float* __restrict__ w_ovl,
            float* __restrict__ o_gtdist){
  __shared__ float2 s_da[360];         // (dist, ang)
  __shared__ float  s_m[NBIN*33];      // per bin: wave w at [w*8+j], j<4 diff, j>=4 dist (pad 33)
  int tid = threadIdx.x;
  int lane = tid & 63, wave = tid >> 6;
  int cnt = counter[0];
  for (int p = blockIdx.x; p < cnt; p += gridDim.x){
    int t = pairs[p];
    int a = t % NA; int bm = t / NA; int b = bm / NM;
    float ax = anc[2*a], ay = anc[2*a+1];
    const float* cc = coor + bm*720;
    for (int i = tid; i < 360; i += 256){
      float dx = cc[2*i]   - ax;
      float dy = cc[2*i+1] - ay;
      float dist = sqrtf(dx*dx + dy*dy);
      float an = atan2f(dy, dx) * 57.29577951308232f;
      if (an < 0.f) an += 360.f;
      s_da[i] = make_float2(dist, an);
    }
    __syncthreads();
    if (lane < NBIN){
      float th = (float)(lane*10);
      float v0=1e30f, v1=1e30f, v2=1e30f, v3=1e30f;
      float d0=0.f, d1=0.f, d2=0.f, d3=0.f;
      int base = wave*90;
      for (int k = 0; k < 90; k++){
        float2 da = s_da[base + k];
        float diff = fabsf(da.y - th);
        diff = fminf(diff, 360.f - diff);
        if (diff < v3){
          v3 = diff; d3 = da.x;
          if (v3 < v2){ float tv=v2; v2=v3; v3=tv; float td=d2; d2=d3; d3=td; }
          if (v2 < v1){ float tv=v1; v1=v2; v2=tv; float td=d1; d1=d2; d2=td; }
          if (v1 < v0){ float tv=v0; v0=v1; v1=tv; float td=d0; d0=d1; d1=td; }
        }
      }
      int mb = lane*33 + wave*8;
      s_m[mb+0]=v0; s_m[mb+1]=v1; s_m[mb+2]=v2; s_m[mb+3]=v3;
      s_m[mb+4]=d0; s_m[mb+5]=d1; s_m[mb+6]=d2; s_m[mb+7]=d3;
    }
    __syncthreads();
    if (wave == 0){
      float sum_min = 0.f, sum_max = 0.f;
      if (lane < NBIN){
        int mb = lane*33;
        float h0=s_m[mb+0], h1=s_m[mb+8], h2=s_m[mb+16], h3=s_m[mb+24];
        int p0=0, p1=0, p2=0, p3=0;
        float v0m = 0.f, dmax = 0.f;
#pragma unroll
        for (int step = 0; step < 4; step++){
          float bv = h0; int bw = 0;
          if (h1 < bv){ bv = h1; bw = 1; }
          if (h2 < bv){ bv = h2; bw = 2; }
          if (h3 < bv){ bv = h3; bw = 3; }
          float dd;
          if (bw == 0){ dd = s_m[mb+4+p0]; p0++; h0 = (p0<4)? s_m[mb+p0]    : 1e30f; }
          else if (bw == 1){ dd = s_m[mb+12+p1]; p1++; h1 = (p1<4)? s_m[mb+8+p1]  : 1e30f; }
          else if (bw == 2){ dd = s_m[mb+20+p2]; p2++; h2 = (p2<4)? s_m[mb+16+p2] : 1e30f; }
          else             { dd = s_m[mb+28+p3]; p3++; h3 = (p3<4)? s_m[mb+24+p3] : 1e30f; }
          if (step == 0) v0m = bv;
          dmax = fmaxf(dmax, dd);
        }
        float dm = (v0m > 3.0f) ? 1e-6f : dmax;
        float dfin = fmaxf(dm, 1e-6f);
        o_gtdist[(size_t)t*NBIN + lane] = dfin;
        float pr = pdb[((size_t)b*NA + a)*NBIN + lane];
        sum_max = fmaxf(dfin, pr);
        sum_min = fmaxf(fminf(dfin, pr), 1e-6f);
      }
      for (int off = 32; off > 0; off >>= 1){
        sum_min += __shfl_down(sum_min, off);
        sum_max += __shfl_down(sum_max, off);
      }
      if (lane == 0){
        float ov = sum_min / sum_max;
        int cls = gl[bm];
        float sc = pds[((size_t)b*NA + a)*NC + cls];
        w_align[t] = sc * ov * ov * ov;
        w_ovl[t]   = ov;
      }
    }
    __syncthreads();
  }
}

// ---------------- top-13 per (b,m): single pass + 512-wide k-way merge ----------------
__global__ __launch_bounds__(512)
void k_topk(const float* __restrict__ w_align, float* __restrict__ w_mask){
  int bm = blockIdx.x;
  const float* al = w_align + (size_t)bm*NA;
  int tid = threadIdx.x;
  __shared__ float sv[512*KTOP];
  __shared__ int   si[512*KTOP];
  __shared__ float wv8[8];
  __shared__ int   wi8[8];

  float v[KTOP]; int ix[KTOP];
#pragma unroll
  for (int j = 0; j < KTOP; j++){ v[j] = -1.f; ix[j] = 0x7fffffff; }
  for (int a = tid; a < NA; a += 512){
    float x = al[a];
    if (x > v[KTOP-1]){
      v[KTOP-1] = x; ix[KTOP-1] = a;
#pragma unroll
      for (int j = KTOP-1; j > 0; j--){
        if (v[j] > v[j-1]){
          float tv = v[j-1]; v[j-1] = v[j]; v[j] = tv;
          int   ti = ix[j-1]; ix[j-1] = ix[j]; ix[j] = ti;
        }
      }
    }
  }
#pragma unroll
  for (int j = 0; j < KTOP; j++){ sv[tid*KTOP+j] = v[j]; si[tid*KTOP+j] = ix[j]; }

  int head = 0;
  int lane = tid & 63, wave = tid >> 6;
  for (int r = 0; r < KTOP; r++){
    float cv = sv[tid*KTOP + head];
    int   ci = si[tid*KTOP + head];
    float rv = cv; int ri = ci;
    for (int off = 32; off > 0; off >>= 1){
      float ov = __shfl_down(rv, off);
      int   oi = __shfl_down(ri, off);
      if (ov > rv || (ov == rv && oi < ri)){ rv = ov; ri = oi; }
    }
    if (lane == 0){ wv8[wave] = rv; wi8[wave] = ri; }
    __syncthreads();
    float Wv = wv8[0]; int Wi = wi8[0];
#pragma unroll
    for (int w = 1; w < 8; w++){
      float ov = wv8[w]; int oi = wi8[w];
      if (ov > Wv || (ov == Wv && oi < Wi)){ Wv = ov; Wi = oi; }
    }
    if (ci == Wi && head < KTOP-1) head++;
    if (tid == 0 && Wv > 0.f) w_mask[(size_t)bm*NA + Wi] = 1.f;
    __syncthreads();
  }
}

// ---------------- per-anchor finalize (+ fused pos_align/pos_ov atomics) --------
__global__ void k_final(const float* __restrict__ w_align, const float* __restrict__ w_ovl,
                        float* __restrict__ w_mask,
                        const int* __restrict__ gl, const float* __restrict__ gtb,
                        float* __restrict__ o_labels, float* __restrict__ o_bboxes,
                        float* __restrict__ o_maskpos, float* __restrict__ o_gtidx,
                        float* __restrict__ o_fg,
                        float* __restrict__ w_pa, float* __restrict__ w_po){
  int t = blockIdx.x*256 + threadIdx.x;
  if (t >= BS*NA) return;
  int a = t % NA, b = t / NA;
  float mp[NM];
  int fg = 0;
#pragma unroll
  for (int m = 0; m < NM; m++){
    mp[m] = w_mask[((size_t)(b*NM+m))*NA + a];
    fg += (mp[m] > 0.f) ? 1 : 0;
  }
  if (fg > 1){
    float bv = -1.f; int bi = 0;
#pragma unroll
    for (int m = 0; m < NM; m++){
      float v = w_ovl[((size_t)(b*NM+m))*NA + a];
      if (v > bv){ bv = v; bi = m; }
    }
#pragma unroll
    for (int m = 0; m < NM; m++){
      mp[m] = (m == bi) ? 1.f : 0.f;
      w_mask[((size_t)(b*NM+m))*NA + a] = mp[m];
    }
    fg = 1;
  }
  int tgt = 0;
#pragma unroll
  for (int m = NM-1; m >= 0; m--) if (mp[m] > 0.f) tgt = m;
#pragma unroll
  for (int m = 0; m < NM; m++) o_maskpos[((size_t)(b*NM+m))*NA + a] = mp[m];
  o_gtidx[t] = (float)tgt;
  o_fg[t] = (fg > 0) ? 1.f : 0.f;
  int lbl = gl[b*NM + tgt]; if (lbl < 0) lbl = 0;
  o_labels[t] = (float)lbl;
  const float* bx = gtb + (b*NM + tgt)*4;
  ((float4*)o_bboxes)[t] = make_float4(bx[0], bx[1], bx[2], bx[3]);
  if (fg > 0){
    int bmx = b*NM + tgt;
    float av = w_align[(size_t)bmx*NA + a];
    float ovv = w_ovl[(size_t)bmx*NA + a];
    // values >= 0 -> uint bit-pattern order == float order
    atomicMax((unsigned int*)&w_pa[bmx], __float_as_uint(av));
    atomicMax((unsigned int*)&w_po[bmx], __float_as_uint(ovv));
  }
}

// ---------------- fused tail: (A) gt_dist mask + centerness, (B) scores --------
#define NB_FIX 1024
__global__ void k_fuse(const int* __restrict__ counter, const int* __restrict__ pairs,
                       const float* __restrict__ w_mask, float* __restrict__ o_gtdist,
                       float* __restrict__ o_cent,
                       const float* __restrict__ w_align,
                       const float* __restrict__ w_pa, const float* __restrict__ w_po,
                       const float* __restrict__ o_labels, const float* __restrict__ o_fg,
                       const float* __restrict__ o_gtidx, float* __restrict__ o_scores){
  if (blockIdx.x < NB_FIX){
    int lane = threadIdx.x & 63, wave = threadIdx.x >> 6;
    int cnt = counter[0];
    for (int p = blockIdx.x*4 + wave; p < cnt; p += NB_FIX*4){
      int t = pairs[p];
      float m = w_mask[t];
      float* row = o_gtdist + (size_t)t*NBIN;
      if (m > 0.f){
        float vmin = 1e30f, vmax = 0.f;
        if (lane < NBIN){
          float v = row[lane];
          vmin = v; vmax = v;
        }
        for (int off = 32; off > 0; off >>= 1){
          vmin = fminf(vmin, __shfl_down(vmin, off));
          vmax = fmaxf(vmax, __shfl_down(vmax, off));
        }
        if (lane == 0) o_cent[t] = sqrtf(vmin / vmax);
      } else {
        if (lane < NBIN) row[lane] = 0.f;
      }
    }
  } else {
    int t = (blockIdx.x - NB_FIX)*256 + threadIdx.x;
    if (t < BS*NA && o_fg[t] > 0.f){
      int a = t % NA, b = t / NA;
      int m = (int)o_gtidx[t];
      int bm = b*NM + m;
      // post-resolution mask has <=1 gt per anchor -> norm = single term
      float av = w_align[(size_t)bm*NA + a];
      float norm = av * w_po[bm] / (w_pa[bm] + 1e-9f);
      int lbl = (int)o_labels[t];
      o_scores[(size_t)t*NC + lbl] = norm;
    }
  }
}

extern "C" void kernel_launch(void* const* d_in, const int* in_sizes, int n_in,
                              void* d_out, int out_size, void* d_ws, size_t ws_size,
                              hipStream_t stream){
  const float* pds  = (const float*)d_in[0]; // (2,8400,80)
  const float* pdb  = (const float*)d_in[1]; // (2,8400,36)
  const float* anc  = (const float*)d_in[2]; // (8400,2)
  const int*   gl   = (const int*)  d_in[3]; // (2,10,1)
  const float* gtb  = (const float*)d_in[4]; // (2,10,4)
  const float* mgt  = (const float*)d_in[5]; // (2,10,1)
  const float* coor = (const float*)d_in[6]; // (2,10,720)

  float* out = (float*)d_out;
  float* o_labels  = out;                                 // 16800
  float* o_bboxes  = o_labels + BS*NA;                    // 67200
  float* o_scores  = o_bboxes + BS*NA*4;                  // 1344000
  float* o_maskpos = o_scores + (size_t)BS*NA*NC;         // 168000
  float* o_gtidx   = o_maskpos + BS*NM*NA;                // 16800
  float* o_gtdist  = o_gtidx + BS*NA;                     // 6048000
  float* o_cent    = o_gtdist + (size_t)BS*NM*NA*NBIN;    // 168000
  float* o_fg      = o_cent + BS*NM*NA;                   // 16800

  float* wf      = (float*)d_ws;
  int*   counter = (int*)d_ws;           // wf[0]
  float* w_align = wf + 16;              // 168000
  float* w_ovl   = w_align + BS*NM*NA;   // 168000
  float* w_mask  = w_ovl + BS*NM*NA;     // 168000
  float* w_pa    = w_mask + BS*NM*NA;    // 20
  float* w_po    = w_pa + BS*NM;         // 20
  int*   w_pairs = (int*)(w_po + BS*NM); // up to 168000

  int n4 = out_size / 4;
  int nz = 16 + 3*BS*NM*NA + 2*BS*NM;
  int nmax = (n4 > nz) ? n4 : nz;
  k_zero<<<(nmax+255)/256, 256, 0, stream>>>((float4*)out, n4, wf, nz);
  k_masklist<<<(BS*NM*NA+255)/256, 256, 0, stream>>>(anc, gtb, mgt, counter, w_pairs);
  k_dist<<<4096, 256, 0, stream>>>(anc, coor, pdb, pds, gl, counter, w_pairs,
                                   w_align, w_ovl, o_gtdist);
  k_topk<<<BS*NM, 512, 0, stream>>>(w_align, w_mask);
  k_final<<<(BS*NA+255)/256, 256, 0, stream>>>(w_align, w_ovl, w_mask, gl, gtb,
                                               o_labels, o_bboxes, o_maskpos, o_gtidx, o_fg,
                                               w_pa, w_po);
  k_fuse<<<NB_FIX + (BS*NA+255)/256, 256, 0, stream>>>(counter, w_pairs, w_mask,
                                                       o_gtdist, o_cent,
                                                       w_align, w_pa, w_po,
                                                       o_labels, o_fg, o_gtidx, o_scores);
}